// Round 6
// baseline (318.444 us; speedup 1.0000x reference)
//
#include <hip/hip_runtime.h>
#include <cstdint>

typedef float floatx4 __attribute__((ext_vector_type(4)));
typedef int intx8 __attribute__((ext_vector_type(8)));

__device__ __forceinline__ unsigned short f2b(float f) {
  union { float f; unsigned u; } v; v.f = f;
  return (unsigned short)((v.u + 0x7FFFu + ((v.u >> 16) & 1u)) >> 16);
}
__device__ __forceinline__ float b2f(unsigned short h) {
  union { unsigned u; float f; } v; v.u = ((unsigned)h) << 16;
  return v.f;
}

__device__ __forceinline__ void gload_lds16(const void* g, void* l) {
  __builtin_amdgcn_global_load_lds(
      (const __attribute__((address_space(1))) void*)g,
      (__attribute__((address_space(3))) void*)l, 16, 0, 0);
}

// ---------------- small prep kernels ----------------

// W (f32) -> fp8 e4m3 of (W * 64); consumed with MX block-scale 2^-6
__global__ void cast_f8x64_kernel(const float* __restrict__ in,
                                  int* __restrict__ out) {
  long i = (long)blockIdx.x * 256 + threadIdx.x;
  float4 v = ((const float4*)in)[i];
  int pk = __builtin_amdgcn_cvt_pk_fp8_f32(v.x * 64.0f, v.y * 64.0f, 0, false);
  pk = __builtin_amdgcn_cvt_pk_fp8_f32(v.z * 64.0f, v.w * 64.0f, pk, true);
  out[i] = pk;
}

// T8[n][m] = fp8(64 * w[n-m]) for m<=n else 0; 2048x2048 bytes
__global__ void build_T8_kernel(const float* __restrict__ w,
                                int* __restrict__ T8) {
  long i = (long)blockIdx.x * 256 + threadIdx.x;  // int index, 512 per row
  int n = (int)(i >> 9);
  int m0 = (int)(i & 511) * 4;
  float v[4];
#pragma unroll
  for (int r = 0; r < 4; ++r) {
    int m = m0 + r;
    v[r] = (m <= n) ? w[n - m] * 64.0f : 0.0f;
  }
  int pk = __builtin_amdgcn_cvt_pk_fp8_f32(v[0], v[1], 0, false);
  pk = __builtin_amdgcn_cvt_pk_fp8_f32(v[2], v[3], pk, true);
  T8[i] = pk;
}

// x (B,2048,1024) f32 -> xT8 (B,1024,2048) fp8 e4m3 (scale 2^0)
__global__ void transpose_cast_f8_kernel(const float* __restrict__ x,
                                         unsigned char* __restrict__ xT) {
  __shared__ float tile[32][33];
  int b = blockIdx.z;
  int n0 = blockIdx.y * 32;
  int d0 = blockIdx.x * 32;
  int tx = threadIdx.x;  // 0..31
  int ty = threadIdx.y;  // 0..7
  for (int i = ty; i < 32; i += 8)
    tile[i][tx] = x[((long)b * 2048 + n0 + i) * 1024 + d0 + tx];
  __syncthreads();
  float a = tile[ty * 4 + 0][tx];
  float c = tile[ty * 4 + 1][tx];
  float e = tile[ty * 4 + 2][tx];
  float f = tile[ty * 4 + 3][tx];
  int pk = __builtin_amdgcn_cvt_pk_fp8_f32(a, c, 0, false);
  pk = __builtin_amdgcn_cvt_pk_fp8_f32(e, f, pk, true);
  *(int*)(xT + ((long)b * 1024 + d0 + tx) * 2048 + n0 + ty * 4) = pk;
}

// ---------------- fp8 GEMM (MX-scaled): C = A @ B^T ----------------
// BM=BN=BK=128, mfma_scale_f32_16x16x128_f8f6f4, 4 waves of 64x64.
// Epilogue: acc -> LDS (f32, 64x128, per-row 16B-rotate swizzle, 2 passes)
//           -> 32 contiguous floats/thread -> convert -> dwordx4 stores.
// GELU=false: Cb = bf16(acc)        (conv out / split-K partial)
// GELU=true : C8 = fp8(gelu(acc+bias[col]))
template <bool GELU, bool TRI>
__global__ __launch_bounds__(256, 4) void gemm_f8(
    const unsigned char* __restrict__ A, const unsigned char* __restrict__ B,
    int NT, int Kstride, int Kloop, long zsA, long zsB, long zsC,
    int rx, int ryb, int gxn, unsigned sclA, unsigned sclB,
    const float* __restrict__ bias,
    unsigned short* __restrict__ Cb, unsigned char* __restrict__ C8) {
  __shared__ __align__(16) unsigned char smem[2 * 16 * 1040];  // 33280 B
  unsigned char* As = smem;
  unsigned char* Bs = smem + 16 * 1040;
  const int tid = threadIdx.x;
  const int wid = tid >> 6;
  const int lane = tid & 63;
  const int quad = lane >> 4;
  const int l16 = lane & 15;
  const int wm = (wid >> 1) * 64;
  const int wn = (wid & 1) * 64;

  // XCD-rectangle block swizzle (xcd = bid&7 round-robin heuristic)
  const int bid = blockIdx.x;
  const int xcd = bid & 7;
  const int ib = bid >> 3;
  const int ci = ib % rx;
  const int ri = ib / rx;
  long bm, bn;
  if (TRI) {
    bm = (long)(ri == 0 ? xcd : 15 - xcd) * 128;
    bn = (long)ci * 128;
  } else {
    const int gx = xcd % gxn;
    const int gy = xcd / gxn;
    bm = (long)(gy * ryb + ri) * 128;
    bn = (long)(gx * rx + ci) * 128;
  }
  const int bz = blockIdx.z;
  const unsigned char* Ab = A + zsA * bz;
  const unsigned char* Bb = B + zsB * bz;

  floatx4 acc[4][4];
#pragma unroll
  for (int i = 0; i < 4; ++i)
#pragma unroll
    for (int j = 0; j < 4; ++j)
      acc[i][j] = floatx4{0.0f, 0.0f, 0.0f, 0.0f};

  // staging: 4 passes x 256 thr x 16B; chunk (p,w) -> LDS base (p*4+w)*1040
  const int srow = tid >> 3;
  const int scol = (tid & 7) * 16;
  const unsigned char* gA[4];
  const unsigned char* gB[4];
  unsigned char* lA[4];
  unsigned char* lB[4];
#pragma unroll
  for (int p = 0; p < 4; ++p) {
    gA[p] = Ab + (bm + p * 32 + srow) * (long)Kstride + scol;
    gB[p] = Bb + (bn + p * 32 + srow) * (long)Kstride + scol;
    lA[p] = As + (p * 4 + wid) * 1040;
    lB[p] = Bs + (p * 4 + wid) * 1040;
  }

  const int kend = TRI ? min(Kloop, (int)bm + 128) : Kloop;
  for (int kk = 0; kk < kend; kk += 128) {
    __syncthreads();
#pragma unroll
    for (int p = 0; p < 4; ++p) {
      gload_lds16(gA[p] + kk, lA[p]);
      gload_lds16(gB[p] + kk, lB[p]);
    }
    __syncthreads();
    intx8 af[4], bfr[4];
#pragma unroll
    for (int i = 0; i < 4; ++i) {
      const int ra = wm + i * 16 + l16;
      const int off = (ra >> 3) * 1040 + (ra & 7) * 128 + quad * 32;
      union { intx8 v; int4 q[2]; } u;
      u.q[0] = *(const int4*)(As + off);
      u.q[1] = *(const int4*)(As + off + 16);
      af[i] = u.v;
    }
#pragma unroll
    for (int j = 0; j < 4; ++j) {
      const int rb = wn + j * 16 + l16;
      const int off = (rb >> 3) * 1040 + (rb & 7) * 128 + quad * 32;
      union { intx8 v; int4 q[2]; } u;
      u.q[0] = *(const int4*)(Bs + off);
      u.q[1] = *(const int4*)(Bs + off + 16);
      bfr[j] = u.v;
    }
#pragma unroll
    for (int i = 0; i < 4; ++i)
#pragma unroll
      for (int j = 0; j < 4; ++j)
        acc[i][j] = __builtin_amdgcn_mfma_scale_f32_16x16x128_f8f6f4(
            af[i], bfr[j], acc[i][j], 0 /*fp8*/, 0 /*fp8*/,
            0, sclA, 0, sclB);
  }

  // ---- epilogue: LDS repack, 2 passes of 64 rows ----
  float bj[4];
  if (GELU) {
#pragma unroll
    for (int j = 0; j < 4; ++j) bj[j] = bias[bn + wn + j * 16 + l16];
  }
  float* cbuf = (float*)smem;          // 64 x 128 f32, row-rotated
  const int rl_r = tid >> 2;           // phase-B row 0..63
  const int seg = tid & 3;             // 32-float segment
#pragma unroll
  for (int p = 0; p < 2; ++p) {
    __syncthreads();
    if ((wid >> 1) == p) {
#pragma unroll
      for (int i = 0; i < 4; ++i)
#pragma unroll
        for (int j = 0; j < 4; ++j)
#pragma unroll
          for (int r = 0; r < 4; ++r) {
            const int rl = i * 16 + quad * 4 + r;
            const int col = wn + j * 16 + l16;
            float v = acc[i][j][r];
            if (GELU) {
              v += bj[j];
              float u = v * (0.7978845608f + 0.0356774081f * v * v);
              float u2 = u * u;
              float t = __fdividef(u * (15.0f + u2), 15.0f + 6.0f * u2);
              t = fminf(fmaxf(t, -1.0f), 1.0f);
              v = 0.5f * v * (1.0f + t);
            }
            cbuf[rl * 128 + ((col + rl * 4) & 127)] = v;
          }
    }
    __syncthreads();
    float4 f[8];
#pragma unroll
    for (int k = 0; k < 8; ++k) {
      const int g = (seg * 8 + k + rl_r) & 31;  // rotate back
      f[k] = *(const float4*)(cbuf + rl_r * 128 + g * 4);
    }
    const long grow = bm + p * 64 + rl_r;
    if (GELU) {
      int4 o[2];
#pragma unroll
      for (int s = 0; s < 2; ++s) {
        int d[4];
#pragma unroll
        for (int q = 0; q < 4; ++q) {
          float4 x4 = f[s * 4 + q];
          int pk = __builtin_amdgcn_cvt_pk_fp8_f32(x4.x, x4.y, 0, false);
          pk = __builtin_amdgcn_cvt_pk_fp8_f32(x4.z, x4.w, pk, true);
          d[q] = pk;
        }
        o[s] = int4{d[0], d[1], d[2], d[3]};
      }
      int4* dst = (int4*)(C8 + (long)bz * zsC + grow * (long)NT + bn + seg * 32);
      dst[0] = o[0];
      dst[1] = o[1];
    } else {
      int4* dst = (int4*)(Cb + (long)bz * zsC + grow * (long)NT + bn + seg * 32);
#pragma unroll
      for (int s = 0; s < 4; ++s) {
        float4 a4 = f[s * 2];
        float4 c4 = f[s * 2 + 1];
        int d0 = (unsigned)f2b(a4.x) | ((unsigned)f2b(a4.y) << 16);
        int d1 = (unsigned)f2b(a4.z) | ((unsigned)f2b(a4.w) << 16);
        int d2 = (unsigned)f2b(c4.x) | ((unsigned)f2b(c4.y) << 16);
        int d3 = (unsigned)f2b(c4.z) | ((unsigned)f2b(c4.w) << 16);
        dst[s] = int4{d0, d1, d2, d3};
      }
    }
  }
}

// ---------------- LN1: v = x + scale[n]*conv; out = LN(v) (bf16 + fp8) ------
__global__ __launch_bounds__(256) void ln1_kernel(
    const unsigned short* __restrict__ conv, const float* __restrict__ x,
    const float* __restrict__ scale, const float* __restrict__ w,
    const float* __restrict__ b, unsigned short* __restrict__ outb,
    int* __restrict__ outf8) {
  const long row = blockIdx.x;
  const int n = (int)(row & 2047);
  const int tid = threadIdx.x;
  float4 xv = ((const float4*)x)[row * 256 + tid];
  ushort4 cv = ((const ushort4*)conv)[row * 256 + tid];
  const float sc = scale[n];
  float4 v;
  v.x = xv.x + sc * b2f(cv.x);
  v.y = xv.y + sc * b2f(cv.y);
  v.z = xv.z + sc * b2f(cv.z);
  v.w = xv.w + sc * b2f(cv.w);
  float s = v.x + v.y + v.z + v.w;
  float ss = v.x * v.x + v.y * v.y + v.z * v.z + v.w * v.w;
#pragma unroll
  for (int off = 32; off > 0; off >>= 1) {
    s += __shfl_down(s, off);
    ss += __shfl_down(ss, off);
  }
  __shared__ float red[8];
  const int wid = tid >> 6, lane = tid & 63;
  if (lane == 0) { red[wid] = s; red[4 + wid] = ss; }
  __syncthreads();
  s = red[0] + red[1] + red[2] + red[3];
  ss = red[4] + red[5] + red[6] + red[7];
  const float mu = s * (1.0f / 1024.0f);
  const float var = ss * (1.0f / 1024.0f) - mu * mu;
  const float rs = rsqrtf(var + 1e-5f);
  float4 wv = ((const float4*)w)[tid];
  float4 bv = ((const float4*)b)[tid];
  float o0 = (v.x - mu) * rs * wv.x + bv.x;
  float o1 = (v.y - mu) * rs * wv.y + bv.y;
  float o2 = (v.z - mu) * rs * wv.z + bv.z;
  float o3 = (v.w - mu) * rs * wv.w + bv.w;
  ushort4 u{f2b(o0), f2b(o1), f2b(o2), f2b(o3)};
  ((ushort4*)outb)[row * 256 + tid] = u;
  int pk = __builtin_amdgcn_cvt_pk_fp8_f32(o0, o1, 0, false);
  pk = __builtin_amdgcn_cvt_pk_fp8_f32(o2, o3, pk, true);
  outf8[row * 256 + tid] = pk;
}

// LN2 fused: v = x1 + scalar*(y0+y1+b2); out = LN(v)*w + b  (y0/y1 bf16 partials)
__global__ __launch_bounds__(256) void ln2_fused_kernel(
    const unsigned short* __restrict__ y0, const unsigned short* __restrict__ y1,
    const unsigned short* __restrict__ x1b, const float* __restrict__ b2,
    const float* __restrict__ scalar_p, const float* __restrict__ w,
    const float* __restrict__ b, float* __restrict__ out) {
  const long row = blockIdx.x;
  const int tid = threadIdx.x;
  ushort4 a4 = ((const ushort4*)y0)[row * 256 + tid];
  ushort4 c4 = ((const ushort4*)y1)[row * 256 + tid];
  ushort4 xr = ((const ushort4*)x1b)[row * 256 + tid];
  float4 bias = ((const float4*)b2)[tid];
  const float scl = scalar_p[0];
  float4 v;
  v.x = b2f(xr.x) + scl * (b2f(a4.x) + b2f(c4.x) + bias.x);
  v.y = b2f(xr.y) + scl * (b2f(a4.y) + b2f(c4.y) + bias.y);
  v.z = b2f(xr.z) + scl * (b2f(a4.z) + b2f(c4.z) + bias.z);
  v.w = b2f(xr.w) + scl * (b2f(a4.w) + b2f(c4.w) + bias.w);
  float s = v.x + v.y + v.z + v.w;
  float ss = v.x * v.x + v.y * v.y + v.z * v.z + v.w * v.w;
#pragma unroll
  for (int off = 32; off > 0; off >>= 1) {
    s += __shfl_down(s, off);
    ss += __shfl_down(ss, off);
  }
  __shared__ float red[8];
  const int wid = tid >> 6, lane = tid & 63;
  if (lane == 0) { red[wid] = s; red[4 + wid] = ss; }
  __syncthreads();
  s = red[0] + red[1] + red[2] + red[3];
  ss = red[4] + red[5] + red[6] + red[7];
  const float mu = s * (1.0f / 1024.0f);
  const float var = ss * (1.0f / 1024.0f) - mu * mu;
  const float rs = rsqrtf(var + 1e-5f);
  float4 wv = ((const float4*)w)[tid];
  float4 bv = ((const float4*)b)[tid];
  float4 o;
  o.x = (v.x - mu) * rs * wv.x + bv.x;
  o.y = (v.y - mu) * rs * wv.y + bv.y;
  o.z = (v.z - mu) * rs * wv.z + bv.z;
  o.w = (v.w - mu) * rs * wv.w + bv.w;
  ((float4*)out)[row * 256 + tid] = o;
}

// ---------------- launch ----------------
extern "C" void kernel_launch(void* const* d_in, const int* in_sizes, int n_in,
                              void* d_out, int out_size, void* d_ws, size_t ws_size,
                              hipStream_t stream) {
  const float* x      = (const float*)d_in[0];
  const float* wconv  = (const float*)d_in[1];
  const float* scale  = (const float*)d_in[2];
  const float* ln1w   = (const float*)d_in[3];
  const float* ln1b   = (const float*)d_in[4];
  const float* W1     = (const float*)d_in[5];
  const float* b1     = (const float*)d_in[6];
  const float* W2     = (const float*)d_in[7];
  const float* b2     = (const float*)d_in[8];
  const float* scalar = (const float*)d_in[9];
  const float* ln2w   = (const float*)d_in[10];
  const float* ln2b   = (const float*)d_in[11];
  float* out = (float*)d_out;

  const unsigned SCL_1  = 0x7F7F7F7Fu;  // 2^0 per-block scales
  const unsigned SCL_64 = 0x79797979u;  // 2^-6 (operand pre-scaled x64)

  char* ws = (char*)d_ws;
  unsigned char* xT8   = (unsigned char*)ws;  ws += (size_t)4 * 1024 * 2048;     //  8 MB
  unsigned char* T8    = (unsigned char*)ws;  ws += (size_t)2048 * 2048;         //  4 MB
  unsigned char* W1f8  = (unsigned char*)ws;  ws += (size_t)4096 * 1024;         //  4 MB
  unsigned char* W2f8  = (unsigned char*)ws;  ws += (size_t)4096 * 1024;         //  4 MB
  unsigned short* convb= (unsigned short*)ws; ws += (size_t)8192 * 1024 * 2;     // 16 MB
  unsigned short* yb   = (unsigned short*)ws; ws += (size_t)2 * 8192 * 1024 * 2; // 32 MB
  unsigned short* x1b  = (unsigned short*)ws; ws += (size_t)8192 * 1024 * 2;     // 16 MB
  unsigned char* x1f8  = (unsigned char*)ws;  ws += (size_t)8192 * 1024;         //  8 MB
  unsigned char* h8    = (unsigned char*)ws;  ws += (size_t)8192 * 4096;         // 32 MB

  // prep
  cast_f8x64_kernel<<<4096, 256, 0, stream>>>(W1, (int*)W1f8);
  cast_f8x64_kernel<<<4096, 256, 0, stream>>>(W2, (int*)W2f8);
  build_T8_kernel<<<4096, 256, 0, stream>>>(wconv, (int*)T8);
  transpose_cast_f8_kernel<<<dim3(32, 64, 4), dim3(32, 8), 0, stream>>>(x, xT8);

  // GEMM1 (fp8, TRI): per batch, conv = T @ xT_b^T -> bf16
  gemm_f8<false, true><<<dim3(128, 1, 4), 256, 0, stream>>>(
      T8, xT8, 1024, 2048, 2048, 0L, (long)1024 * 2048, (long)2048 * 1024,
      8, 0, 0, SCL_64, SCL_1, nullptr, convb, nullptr);
  // LN1: x1 = LN(x + scale*conv) -> bf16 + fp8
  ln1_kernel<<<8192, 256, 0, stream>>>(convb, x, scale, ln1w, ln1b, x1b, (int*)x1f8);
  // GEMM2 (fp8): h = gelu(x1 @ W1^T + b1) -> fp8; rect 16x16, XCD grid 2 wide
  gemm_f8<true, false><<<dim3(2048, 1, 1), 256, 0, stream>>>(
      x1f8, W1f8, 4096, 1024, 1024, 0L, 0L, 0L,
      16, 16, 2, SCL_1, SCL_64, b1, nullptr, h8);
  // GEMM3 (fp8) split-K=2: yb = bf16 partial h @ W2^T; rect 8x8 per XCD
  gemm_f8<false, false><<<dim3(512, 1, 2), 256, 0, stream>>>(
      h8, W2f8, 1024, 4096, 2048, 2048L, 2048L, (long)8192 * 1024,
      8, 8, 1, SCL_1, SCL_64, nullptr, yb, nullptr);
  // LN2 fused: out = LN(x1 + scalar*(yb0+yb1+b2))
  ln2_fused_kernel<<<8192, 256, 0, stream>>>(
      yb, yb + (size_t)8192 * 1024, x1b, b2, scalar, ln2w, ln2b, out);
}

// Round 7
// 302.365 us; speedup vs baseline: 1.0532x; 1.0532x over previous
//
#include <hip/hip_runtime.h>
#include <cstdint>

typedef float floatx4 __attribute__((ext_vector_type(4)));
typedef int intx8 __attribute__((ext_vector_type(8)));

__device__ __forceinline__ unsigned short f2b(float f) {
  union { float f; unsigned u; } v; v.f = f;
  return (unsigned short)((v.u + 0x7FFFu + ((v.u >> 16) & 1u)) >> 16);
}
__device__ __forceinline__ float b2f(unsigned short h) {
  union { unsigned u; float f; } v; v.u = ((unsigned)h) << 16;
  return v.f;
}

__device__ __forceinline__ void gload_lds16(const void* g, void* l) {
  __builtin_amdgcn_global_load_lds(
      (const __attribute__((address_space(1))) void*)g,
      (__attribute__((address_space(3))) void*)l, 16, 0, 0);
}

// ---------------- small prep kernels ----------------

// W (f32) -> fp8 e4m3 of (W * 64); consumed with MX block-scale 2^-6
__global__ void cast_f8x64_kernel(const float* __restrict__ in,
                                  int* __restrict__ out) {
  long i = (long)blockIdx.x * 256 + threadIdx.x;
  float4 v = ((const float4*)in)[i];
  int pk = __builtin_amdgcn_cvt_pk_fp8_f32(v.x * 64.0f, v.y * 64.0f, 0, false);
  pk = __builtin_amdgcn_cvt_pk_fp8_f32(v.z * 64.0f, v.w * 64.0f, pk, true);
  out[i] = pk;
}

// T8[n][m] = fp8(64 * w[n-m]) for m<=n else 0; 2048x2048 bytes
__global__ void build_T8_kernel(const float* __restrict__ w,
                                int* __restrict__ T8) {
  long i = (long)blockIdx.x * 256 + threadIdx.x;  // int index, 512 per row
  int n = (int)(i >> 9);
  int m0 = (int)(i & 511) * 4;
  float v[4];
#pragma unroll
  for (int r = 0; r < 4; ++r) {
    int m = m0 + r;
    v[r] = (m <= n) ? w[n - m] * 64.0f : 0.0f;
  }
  int pk = __builtin_amdgcn_cvt_pk_fp8_f32(v[0], v[1], 0, false);
  pk = __builtin_amdgcn_cvt_pk_fp8_f32(v[2], v[3], pk, true);
  T8[i] = pk;
}

// x (B,2048,1024) f32 -> xT8 (B,1024,2048) fp8 e4m3 (scale 2^0)
__global__ void transpose_cast_f8_kernel(const float* __restrict__ x,
                                         unsigned char* __restrict__ xT) {
  __shared__ float tile[32][33];
  int b = blockIdx.z;
  int n0 = blockIdx.y * 32;
  int d0 = blockIdx.x * 32;
  int tx = threadIdx.x;  // 0..31
  int ty = threadIdx.y;  // 0..7
  for (int i = ty; i < 32; i += 8)
    tile[i][tx] = x[((long)b * 2048 + n0 + i) * 1024 + d0 + tx];
  __syncthreads();
  float a = tile[ty * 4 + 0][tx];
  float c = tile[ty * 4 + 1][tx];
  float e = tile[ty * 4 + 2][tx];
  float f = tile[ty * 4 + 3][tx];
  int pk = __builtin_amdgcn_cvt_pk_fp8_f32(a, c, 0, false);
  pk = __builtin_amdgcn_cvt_pk_fp8_f32(e, f, pk, true);
  *(int*)(xT + ((long)b * 1024 + d0 + tx) * 2048 + n0 + ty * 4) = pk;
}

// ---------------- fp8 GEMM (MX-scaled): C = A @ B^T ----------------
// BM=BN=BK=128, mfma_scale_f32_16x16x128_f8f6f4, 4 waves of 64x64.
// Epilogue: acc -> LDS (f32, 64x128, per-row 16B-rotate swizzle, 2 passes)
//   -> phase B: thread (row=tid>>2, ls=tid&3) handles chunks c=ls+4s so each
//      store INSTRUCTION covers 64B contiguous per row (full sectors, no RMW).
// GELU=false: Cb = bf16(acc)        (conv out / split-K partial)
// GELU=true : C8 = fp8(gelu(acc+bias[col]))
template <bool GELU, bool TRI>
__global__ __launch_bounds__(256, 4) void gemm_f8(
    const unsigned char* __restrict__ A, const unsigned char* __restrict__ B,
    int NT, int Kstride, int Kloop, long zsA, long zsB, long zsC,
    int rx, int ryb, int gxn, unsigned sclA, unsigned sclB,
    const float* __restrict__ bias,
    unsigned short* __restrict__ Cb, unsigned char* __restrict__ C8) {
  __shared__ __align__(16) unsigned char smem[2 * 16 * 1040];  // 33280 B
  unsigned char* As = smem;
  unsigned char* Bs = smem + 16 * 1040;
  const int tid = threadIdx.x;
  const int wid = tid >> 6;
  const int lane = tid & 63;
  const int quad = lane >> 4;
  const int l16 = lane & 15;
  const int wm = (wid >> 1) * 64;
  const int wn = (wid & 1) * 64;

  // XCD-rectangle block swizzle (xcd = bid&7 round-robin heuristic)
  const int bid = blockIdx.x;
  const int xcd = bid & 7;
  const int ib = bid >> 3;
  const int ci = ib % rx;
  const int ri = ib / rx;
  long bm, bn;
  if (TRI) {
    bm = (long)(ri == 0 ? xcd : 15 - xcd) * 128;
    bn = (long)ci * 128;
  } else {
    const int gx = xcd % gxn;
    const int gy = xcd / gxn;
    bm = (long)(gy * ryb + ri) * 128;
    bn = (long)(gx * rx + ci) * 128;
  }
  const int bz = blockIdx.z;
  const unsigned char* Ab = A + zsA * bz;
  const unsigned char* Bb = B + zsB * bz;

  floatx4 acc[4][4];
#pragma unroll
  for (int i = 0; i < 4; ++i)
#pragma unroll
    for (int j = 0; j < 4; ++j)
      acc[i][j] = floatx4{0.0f, 0.0f, 0.0f, 0.0f};

  // staging: 4 passes x 256 thr x 16B; chunk (p,w) -> LDS base (p*4+w)*1040
  const int srow = tid >> 3;
  const int scol = (tid & 7) * 16;
  const unsigned char* gA[4];
  const unsigned char* gB[4];
  unsigned char* lA[4];
  unsigned char* lB[4];
#pragma unroll
  for (int p = 0; p < 4; ++p) {
    gA[p] = Ab + (bm + p * 32 + srow) * (long)Kstride + scol;
    gB[p] = Bb + (bn + p * 32 + srow) * (long)Kstride + scol;
    lA[p] = As + (p * 4 + wid) * 1040;
    lB[p] = Bs + (p * 4 + wid) * 1040;
  }

  const int kend = TRI ? min(Kloop, (int)bm + 128) : Kloop;
  for (int kk = 0; kk < kend; kk += 128) {
    __syncthreads();
#pragma unroll
    for (int p = 0; p < 4; ++p) {
      gload_lds16(gA[p] + kk, lA[p]);
      gload_lds16(gB[p] + kk, lB[p]);
    }
    __syncthreads();
    intx8 af[4], bfr[4];
#pragma unroll
    for (int i = 0; i < 4; ++i) {
      const int ra = wm + i * 16 + l16;
      const int off = (ra >> 3) * 1040 + (ra & 7) * 128 + quad * 32;
      union { intx8 v; int4 q[2]; } u;
      u.q[0] = *(const int4*)(As + off);
      u.q[1] = *(const int4*)(As + off + 16);
      af[i] = u.v;
    }
#pragma unroll
    for (int j = 0; j < 4; ++j) {
      const int rb = wn + j * 16 + l16;
      const int off = (rb >> 3) * 1040 + (rb & 7) * 128 + quad * 32;
      union { intx8 v; int4 q[2]; } u;
      u.q[0] = *(const int4*)(Bs + off);
      u.q[1] = *(const int4*)(Bs + off + 16);
      bfr[j] = u.v;
    }
#pragma unroll
    for (int i = 0; i < 4; ++i)
#pragma unroll
      for (int j = 0; j < 4; ++j)
        acc[i][j] = __builtin_amdgcn_mfma_scale_f32_16x16x128_f8f6f4(
            af[i], bfr[j], acc[i][j], 0 /*fp8*/, 0 /*fp8*/,
            0, sclA, 0, sclB);
  }

  // ---- epilogue: LDS repack, 2 passes of 64 rows ----
  float bj[4];
  if (GELU) {
#pragma unroll
    for (int j = 0; j < 4; ++j) bj[j] = bias[bn + wn + j * 16 + l16];
  }
  float* cbuf = (float*)smem;          // 64 x 128 f32, row-rotated by row*4
  const int rowB = tid >> 2;           // phase-B row 0..63
  const int ls = tid & 3;
#pragma unroll
  for (int p = 0; p < 2; ++p) {
    __syncthreads();
    if ((wid >> 1) == p) {
#pragma unroll
      for (int i = 0; i < 4; ++i)
#pragma unroll
        for (int j = 0; j < 4; ++j)
#pragma unroll
          for (int r = 0; r < 4; ++r) {
            const int rl = i * 16 + quad * 4 + r;
            const int col = wn + j * 16 + l16;
            float v = acc[i][j][r];
            if (GELU) {
              v += bj[j];
              float u = v * (0.7978845608f + 0.0356774081f * v * v);
              float u2 = u * u;
              float t = __fdividef(u * (15.0f + u2), 15.0f + 6.0f * u2);
              t = fminf(fmaxf(t, -1.0f), 1.0f);
              v = 0.5f * v * (1.0f + t);
            }
            cbuf[rl * 128 + ((col + rl * 4) & 127)] = v;
          }
    }
    __syncthreads();
    const long grow = bm + p * 64 + rowB;
    const float* rb = cbuf + rowB * 128;
    const int rot = rowB * 4;
    if (GELU) {
      // 8 chunks of 16 fp8 per row; thread does c = ls + 4s, s=0..1
      int4* dst = (int4*)(C8 + (long)bz * zsC + grow * (long)NT + bn);
#pragma unroll
      for (int s = 0; s < 2; ++s) {
        const int c = ls + s * 4;
        int d[4];
#pragma unroll
        for (int q = 0; q < 4; ++q) {
          float4 f = *(const float4*)(rb + ((c * 16 + q * 4 + rot) & 127));
          int pk = __builtin_amdgcn_cvt_pk_fp8_f32(f.x, f.y, 0, false);
          pk = __builtin_amdgcn_cvt_pk_fp8_f32(f.z, f.w, pk, true);
          d[q] = pk;
        }
        dst[c] = int4{d[0], d[1], d[2], d[3]};
      }
    } else {
      // 16 chunks of 8 bf16 per row; thread does c = ls + 4s, s=0..3
      int4* dst = (int4*)(Cb + (long)bz * zsC + grow * (long)NT + bn);
#pragma unroll
      for (int s = 0; s < 4; ++s) {
        const int c = ls + s * 4;
        int dd[4];
#pragma unroll
        for (int q = 0; q < 2; ++q) {
          float4 f = *(const float4*)(rb + ((c * 8 + q * 4 + rot) & 127));
          dd[q * 2 + 0] = (unsigned)f2b(f.x) | ((unsigned)f2b(f.y) << 16);
          dd[q * 2 + 1] = (unsigned)f2b(f.z) | ((unsigned)f2b(f.w) << 16);
        }
        dst[c] = int4{dd[0], dd[1], dd[2], dd[3]};
      }
    }
  }
}

// ---------------- LN1: v = x + scale[n]*conv; out = LN(v) (bf16 + fp8) ------
__global__ __launch_bounds__(256) void ln1_kernel(
    const unsigned short* __restrict__ conv, const float* __restrict__ x,
    const float* __restrict__ scale, const float* __restrict__ w,
    const float* __restrict__ b, unsigned short* __restrict__ outb,
    int* __restrict__ outf8) {
  const long row = blockIdx.x;
  const int n = (int)(row & 2047);
  const int tid = threadIdx.x;
  float4 xv = ((const float4*)x)[row * 256 + tid];
  ushort4 cv = ((const ushort4*)conv)[row * 256 + tid];
  const float sc = scale[n];
  float4 v;
  v.x = xv.x + sc * b2f(cv.x);
  v.y = xv.y + sc * b2f(cv.y);
  v.z = xv.z + sc * b2f(cv.z);
  v.w = xv.w + sc * b2f(cv.w);
  float s = v.x + v.y + v.z + v.w;
  float ss = v.x * v.x + v.y * v.y + v.z * v.z + v.w * v.w;
#pragma unroll
  for (int off = 32; off > 0; off >>= 1) {
    s += __shfl_down(s, off);
    ss += __shfl_down(ss, off);
  }
  __shared__ float red[8];
  const int wid = tid >> 6, lane = tid & 63;
  if (lane == 0) { red[wid] = s; red[4 + wid] = ss; }
  __syncthreads();
  s = red[0] + red[1] + red[2] + red[3];
  ss = red[4] + red[5] + red[6] + red[7];
  const float mu = s * (1.0f / 1024.0f);
  const float var = ss * (1.0f / 1024.0f) - mu * mu;
  const float rs = rsqrtf(var + 1e-5f);
  float4 wv = ((const float4*)w)[tid];
  float4 bv = ((const float4*)b)[tid];
  float o0 = (v.x - mu) * rs * wv.x + bv.x;
  float o1 = (v.y - mu) * rs * wv.y + bv.y;
  float o2 = (v.z - mu) * rs * wv.z + bv.z;
  float o3 = (v.w - mu) * rs * wv.w + bv.w;
  ushort4 u{f2b(o0), f2b(o1), f2b(o2), f2b(o3)};
  ((ushort4*)outb)[row * 256 + tid] = u;
  int pk = __builtin_amdgcn_cvt_pk_fp8_f32(o0, o1, 0, false);
  pk = __builtin_amdgcn_cvt_pk_fp8_f32(o2, o3, pk, true);
  outf8[row * 256 + tid] = pk;
}

// LN2 fused: v = x1 + scalar*(y0+y1+b2); out = LN(v)*w + b  (y0/y1 bf16 partials)
__global__ __launch_bounds__(256) void ln2_fused_kernel(
    const unsigned short* __restrict__ y0, const unsigned short* __restrict__ y1,
    const unsigned short* __restrict__ x1b, const float* __restrict__ b2,
    const float* __restrict__ scalar_p, const float* __restrict__ w,
    const float* __restrict__ b, float* __restrict__ out) {
  const long row = blockIdx.x;
  const int tid = threadIdx.x;
  ushort4 a4 = ((const ushort4*)y0)[row * 256 + tid];
  ushort4 c4 = ((const ushort4*)y1)[row * 256 + tid];
  ushort4 xr = ((const ushort4*)x1b)[row * 256 + tid];
  float4 bias = ((const float4*)b2)[tid];
  const float scl = scalar_p[0];
  float4 v;
  v.x = b2f(xr.x) + scl * (b2f(a4.x) + b2f(c4.x) + bias.x);
  v.y = b2f(xr.y) + scl * (b2f(a4.y) + b2f(c4.y) + bias.y);
  v.z = b2f(xr.z) + scl * (b2f(a4.z) + b2f(c4.z) + bias.z);
  v.w = b2f(xr.w) + scl * (b2f(a4.w) + b2f(c4.w) + bias.w);
  float s = v.x + v.y + v.z + v.w;
  float ss = v.x * v.x + v.y * v.y + v.z * v.z + v.w * v.w;
#pragma unroll
  for (int off = 32; off > 0; off >>= 1) {
    s += __shfl_down(s, off);
    ss += __shfl_down(ss, off);
  }
  __shared__ float red[8];
  const int wid = tid >> 6, lane = tid & 63;
  if (lane == 0) { red[wid] = s; red[4 + wid] = ss; }
  __syncthreads();
  s = red[0] + red[1] + red[2] + red[3];
  ss = red[4] + red[5] + red[6] + red[7];
  const float mu = s * (1.0f / 1024.0f);
  const float var = ss * (1.0f / 1024.0f) - mu * mu;
  const float rs = rsqrtf(var + 1e-5f);
  float4 wv = ((const float4*)w)[tid];
  float4 bv = ((const float4*)b)[tid];
  float4 o;
  o.x = (v.x - mu) * rs * wv.x + bv.x;
  o.y = (v.y - mu) * rs * wv.y + bv.y;
  o.z = (v.z - mu) * rs * wv.z + bv.z;
  o.w = (v.w - mu) * rs * wv.w + bv.w;
  ((float4*)out)[row * 256 + tid] = o;
}

// ---------------- launch ----------------
extern "C" void kernel_launch(void* const* d_in, const int* in_sizes, int n_in,
                              void* d_out, int out_size, void* d_ws, size_t ws_size,
                              hipStream_t stream) {
  const float* x      = (const float*)d_in[0];
  const float* wconv  = (const float*)d_in[1];
  const float* scale  = (const float*)d_in[2];
  const float* ln1w   = (const float*)d_in[3];
  const float* ln1b   = (const float*)d_in[4];
  const float* W1     = (const float*)d_in[5];
  const float* b1     = (const float*)d_in[6];
  const float* W2     = (const float*)d_in[7];
  const float* b2     = (const float*)d_in[8];
  const float* scalar = (const float*)d_in[9];
  const float* ln2w   = (const float*)d_in[10];
  const float* ln2b   = (const float*)d_in[11];
  float* out = (float*)d_out;

  const unsigned SCL_1  = 0x7F7F7F7Fu;  // 2^0 per-block scales
  const unsigned SCL_64 = 0x79797979u;  // 2^-6 (operand pre-scaled x64)

  char* ws = (char*)d_ws;
  unsigned char* xT8   = (unsigned char*)ws;  ws += (size_t)4 * 1024 * 2048;     //  8 MB
  unsigned char* T8    = (unsigned char*)ws;  ws += (size_t)2048 * 2048;         //  4 MB
  unsigned char* W1f8  = (unsigned char*)ws;  ws += (size_t)4096 * 1024;         //  4 MB
  unsigned char* W2f8  = (unsigned char*)ws;  ws += (size_t)4096 * 1024;         //  4 MB
  unsigned short* convb= (unsigned short*)ws; ws += (size_t)8192 * 1024 * 2;     // 16 MB
  unsigned short* yb   = (unsigned short*)ws; ws += (size_t)2 * 8192 * 1024 * 2; // 32 MB
  unsigned short* x1b  = (unsigned short*)ws; ws += (size_t)8192 * 1024 * 2;     // 16 MB
  unsigned char* x1f8  = (unsigned char*)ws;  ws += (size_t)8192 * 1024;         //  8 MB
  unsigned char* h8    = (unsigned char*)ws;  ws += (size_t)8192 * 4096;         // 32 MB

  // prep
  cast_f8x64_kernel<<<4096, 256, 0, stream>>>(W1, (int*)W1f8);
  cast_f8x64_kernel<<<4096, 256, 0, stream>>>(W2, (int*)W2f8);
  build_T8_kernel<<<4096, 256, 0, stream>>>(wconv, (int*)T8);
  transpose_cast_f8_kernel<<<dim3(32, 64, 4), dim3(32, 8), 0, stream>>>(x, xT8);

  // GEMM1 (fp8, TRI): per batch, conv = T @ xT_b^T -> bf16
  gemm_f8<false, true><<<dim3(128, 1, 4), 256, 0, stream>>>(
      T8, xT8, 1024, 2048, 2048, 0L, (long)1024 * 2048, (long)2048 * 1024,
      8, 0, 0, SCL_64, SCL_1, nullptr, convb, nullptr);
  // LN1: x1 = LN(x + scale*conv) -> bf16 + fp8
  ln1_kernel<<<8192, 256, 0, stream>>>(convb, x, scale, ln1w, ln1b, x1b, (int*)x1f8);
  // GEMM2 (fp8): h = gelu(x1 @ W1^T + b1) -> fp8; rect 16x16, XCD grid 2 wide
  gemm_f8<true, false><<<dim3(2048, 1, 1), 256, 0, stream>>>(
      x1f8, W1f8, 4096, 1024, 1024, 0L, 0L, 0L,
      16, 16, 2, SCL_1, SCL_64, b1, nullptr, h8);
  // GEMM3 (fp8) split-K=2: yb = bf16 partial h @ W2^T; rect 8x8 per XCD
  gemm_f8<false, false><<<dim3(512, 1, 2), 256, 0, stream>>>(
      h8, W2f8, 1024, 4096, 2048, 2048L, 2048L, (long)8192 * 1024,
      8, 8, 1, SCL_1, SCL_64, nullptr, yb, nullptr);
  // LN2 fused: out = LN(x1 + scalar*(yb0+yb1+b2))
  ln2_fused_kernel<<<8192, 256, 0, stream>>>(
      yb, yb + (size_t)8192 * 1024, x1b, b2, scalar, ln2w, ln2b, out);
}